// Round 4
// baseline (1716.707 us; speedup 1.0000x reference)
//
#include <hip/hip_runtime.h>

#define NTOK   8192
#define DMODEL 1024
#define NATOM  16384

typedef _Float16 half8  __attribute__((ext_vector_type(8)));
typedef _Float16 half4_t __attribute__((ext_vector_type(4)));
typedef float    f32x4  __attribute__((ext_vector_type(4)));

// async global->LDS, 16B per lane; LDS dest is wave-uniform base + lane*16
#define GLOAD_LDS16(gsrc, ldst) \
  __builtin_amdgcn_global_load_lds((const __attribute__((address_space(1))) unsigned int*)(gsrc), \
                                   (__attribute__((address_space(3))) unsigned int*)(ldst), 16, 0, 0)

// ---------------- prep: fp32 -> fp16 (x only) ----------------
__global__ void cvt_f32_f16(const float* __restrict__ in, _Float16* __restrict__ out, int n4) {
  int i = blockIdx.x * 256 + threadIdx.x;
  if (i >= n4) return;
  float4 v = ((const float4*)in)[i];
  half4_t h;
  h[0] = (_Float16)v.x; h[1] = (_Float16)v.y; h[2] = (_Float16)v.z; h[3] = (_Float16)v.w;
  ((half4_t*)out)[i] = h;
}

// ---------------- prep: dict f32 -> Dh [16384,1024] f16 AND dT [1024,16384] f16 ----------------
__global__ void transpose_dict(const float* __restrict__ dict,
                               _Float16* __restrict__ Dh, _Float16* __restrict__ dT) {
  __shared__ _Float16 tile[64][68];
  int a0 = blockIdx.x * 64;   // atom tile
  int d0 = blockIdx.y * 64;   // dim tile
  int tid = threadIdx.x;
  int c = tid & 63;
  int r0 = tid >> 6;
  #pragma unroll
  for (int i = 0; i < 16; i++) {
    int r = r0 + i * 4;
    _Float16 h = (_Float16)dict[(size_t)(a0 + r) * DMODEL + d0 + c];
    tile[r][c] = h;
    Dh[(size_t)(a0 + r) * DMODEL + d0 + c] = h;
  }
  __syncthreads();
  #pragma unroll
  for (int i = 0; i < 16; i++) {
    int rd = r0 + i * 4;
    dT[(size_t)(d0 + rd) * NATOM + a0 + c] = tile[c][rd];
  }
}

__global__ void zero_lsum(float* __restrict__ lsum) {
  lsum[blockIdx.x * 256 + threadIdx.x] = 0.0f;
}

// staging helper: 128 rows x 32 k, XOR k-chunk swizzle on the global source side
__device__ __forceinline__ void stage_ab(const _Float16* __restrict__ A,
                                         const _Float16* __restrict__ B,
                                         _Float16* As, _Float16* Bs,
                                         size_t arow0, size_t brow0, size_t ldk,
                                         int k0, int tid) {
  #pragma unroll
  for (int i = 0; i < 2; i++) {
    int L = tid + i * 256;               // 0..511 = 128 rows x 4 chunks
    int r = L >> 2, pc = L & 3;
    int c = pc ^ ((r >> 1) & 3);
    GLOAD_LDS16(A + (arow0 + r) * ldk + k0 + c * 8, As + (size_t)L * 8);
    GLOAD_LDS16(B + (brow0 + r) * ldk + k0 + c * 8, Bs + (size_t)L * 8);
  }
}

// ---------------- kernel 1: E = mask ? exp(x @ dict^T) : 0, + row-tile sum/max ----------------
// 128x128 tile, BK=32, double-buffered staging, 4 waves (2x2), mfma_f32_16x16x32_f16.
// Mask (512 MB, the dominant HBM stream) is loaded DURING the K-loop as int4 and bit-packed
// into a 2 KB LDS region past the epilogue area -> overlapped with GEMM instead of a tail burst.
__launch_bounds__(256, 4)
__global__ void score_kernel(const _Float16* __restrict__ Xh,
                             const _Float16* __restrict__ Dh,
                             const int* __restrict__ mask,
                             _Float16* __restrict__ E,
                             float* __restrict__ lsum,
                             _Float16* __restrict__ Tmax) {   // [128 tiles][8192 tokens]
  __shared__ _Float16 lds[18432];   // dbuf staging 2x8192 | epilogue 128x136=17408 | mask bits 1024
  char* ldsM = (char*)(lds + 17408);       // 2048 bytes: 128 rows x 16B (128 bits/row)
  const int tid  = threadIdx.x;
  const int lane = tid & 63;
  const int wave = tid >> 6;
  const int wm = wave >> 1, wn = wave & 1;
  const int m0 = blockIdx.y * 128;         // token tile
  const int n0 = blockIdx.x * 128;         // atom tile

  const int frow = lane & 15;
  const int fkc  = lane >> 4;

  // mask ownership: thread covers row mr, cols mh*64..mh*64+63 (16 int4 loads -> 8 packed bytes)
  const int mr = tid >> 1, mh = tid & 1;
  const int* mrow = mask + (size_t)(m0 + mr) * NATOM + n0 + mh * 64;

  f32x4 acc[4][4] = {};
  int4 mv;
  unsigned int mbits = 0;

  stage_ab(Xh, Dh, lds, lds + 4096, m0, n0, DMODEL, 0, tid);
  int cur = 0;
  auto kstep = [&](int it, int phase) {
    __syncthreads();                       // drains vmcnt: buf[cur] ready (issued 1 compute ago)
    if (it + 1 < DMODEL / 32)
      stage_ab(Xh, Dh, lds + (cur ^ 1) * 8192, lds + (cur ^ 1) * 8192 + 4096,
               m0, n0, DMODEL, (it + 1) * 32, tid);
    // mask streaming: one int4 every 2 iters, one packed byte every 4 iters
    if (phase == 0) mv = *(const int4*)(mrow + (it >> 1) * 4);
    else if (phase == 1)
      mbits = (mv.x != 0) | ((mv.y != 0) << 1) | ((mv.z != 0) << 2) | ((mv.w != 0) << 3);
    else if (phase == 2) mv = *(const int4*)(mrow + (it >> 1) * 4);
    else {
      mbits |= ((mv.x != 0) << 4) | ((mv.y != 0) << 5) | ((mv.z != 0) << 6) | ((mv.w != 0) << 7);
      ldsM[mr * 16 + mh * 8 + (it >> 2)] = (char)mbits;
    }
    _Float16* As = lds + cur * 8192;
    _Float16* Bs = As + 4096;
    half8 af[4], bf[4];
    #pragma unroll
    for (int i = 0; i < 4; i++) {
      int ar = wm * 64 + i * 16 + frow;
      int br = wn * 64 + i * 16 + frow;
      af[i] = *(const half8*)&As[ar * 32 + (fkc ^ ((ar >> 1) & 3)) * 8];
      bf[i] = *(const half8*)&Bs[br * 32 + (fkc ^ ((br >> 1) & 3)) * 8];
    }
    #pragma unroll
    for (int i = 0; i < 4; i++)
      #pragma unroll
      for (int j = 0; j < 4; j++)
        acc[i][j] = __builtin_amdgcn_mfma_f32_16x16x32_f16(af[i], bf[j], acc[i][j], 0, 0, 0);
    cur ^= 1;
  };
  for (int it4 = 0; it4 < 8; ++it4) {
    kstep(it4 * 4 + 0, 0); kstep(it4 * 4 + 1, 1);
    kstep(it4 * 4 + 2, 2); kstep(it4 * 4 + 3, 3);
  }

  __syncthreads();                          // mask bits + all staging complete
  // epilogue: C/D layout col=lane&15, row=(lane>>4)*4+reg. mask(bit from LDS)+exp -> LDS -> store.
  const int cr = (lane >> 4) * 4;
  const int cc = lane & 15;
  #pragma unroll
  for (int i = 0; i < 4; i++) {
    unsigned long long rb[4];
    #pragma unroll
    for (int r = 0; r < 4; r++)
      rb[r] = *(const unsigned long long*)&ldsM[(wm * 64 + i * 16 + cr + r) * 16 + wn * 8];
    #pragma unroll
    for (int j = 0; j < 4; j++) {
      #pragma unroll
      for (int r = 0; r < 4; r++) {
        int lr = wm * 64 + i * 16 + cr + r;
        int lc = wn * 64 + j * 16 + cc;
        unsigned int mk = (unsigned int)(rb[r] >> (j * 16 + cc)) & 1u;
        float e = mk ? __expf(acc[i][j][r]) : 0.0f;   // scores bounded |s|<=11: no max-subtract
        lds[lr * 136 + lc] = (_Float16)e;
      }
    }
  }
  __syncthreads();
  // coalesced E store
  #pragma unroll
  for (int i = 0; i < 8; i++) {
    int chunk = i * 256 + tid;
    int r  = chunk >> 4;
    int c8 = (chunk & 15) * 8;
    *(half8*)&E[(size_t)(m0 + r) * NATOM + n0 + c8] = *(const half8*)&lds[r * 136 + c8];
  }
  // per-row partial sum (-> atomic lsum) and tile max (-> Tmax, tile-major for coalesced store)
  {
    int r = tid >> 1, h = tid & 1;
    const _Float16* rowp = &lds[r * 136 + h * 64];
    float s = 0.0f, m = 0.0f;
    #pragma unroll
    for (int i = 0; i < 8; i++) {
      half8 v = *(const half8*)&rowp[i * 8];
      #pragma unroll
      for (int j = 0; j < 8; j++) { float f = (float)v[j]; s += f; m = fmaxf(m, f); }
    }
    s += __shfl_xor(s, 1, 64);
    m = fmaxf(m, __shfl_xor(m, 1, 64));
    if (h == 0) {
      atomicAdd(&lsum[m0 + r], s);
      Tmax[(size_t)blockIdx.x * NTOK + m0 + r] = (_Float16)m;
    }
  }
}

// ---------------- kernel 2: sparse argmax scan (1 wave / token) ----------------
__global__ void scan_lite(const _Float16* __restrict__ E,
                          const _Float16* __restrict__ Tmax,
                          const float* __restrict__ x,
                          const float* __restrict__ dict,
                          float* __restrict__ argout) {
  const int t = blockIdx.x;
  const int lane = threadIdx.x;            // 0..63
  float m0 = (float)Tmax[(size_t)lane * NTOK + t];
  float m1 = (float)Tmax[(size_t)(64 + lane) * NTOK + t];
  float mx = fmaxf(m0, m1);
  #pragma unroll
  for (int off = 32; off > 0; off >>= 1) mx = fmaxf(mx, __shfl_xor(mx, off, 64));

  __shared__ int cnt;
  __shared__ int cand[32];
  __shared__ double csc[32];
  if (lane == 0) cnt = 0;
  __syncthreads();

  if (mx > 0.0f) {
    float thr = 0.98f * mx;   // margin ln(1/0.98)=0.020 ~ 84 sigma of fp16-GEMM score error
    unsigned long long q0 = __ballot(m0 >= thr);
    unsigned long long q1 = __ballot(m1 >= thr);
    while (q0 | q1) {
      int tile;
      if (q0) { tile = __ffsll(q0) - 1; q0 &= q0 - 1; }
      else    { tile = 64 + __ffsll(q1) - 1; q1 &= q1 - 1; }
      const _Float16* ep = E + (size_t)t * NATOM + tile * 128;
      float e0 = (float)ep[lane], e1 = (float)ep[64 + lane];
      if (e0 >= thr) { int p = atomicAdd(&cnt, 1); if (p < 32) cand[p] = tile * 128 + lane; }
      if (e1 >= thr) { int p = atomicAdd(&cnt, 1); if (p < 32) cand[p] = tile * 128 + 64 + lane; }
    }
  }
  __syncthreads();
  int nc = min(cnt, 32);
  const float* xr = x + (size_t)t * DMODEL;
  for (int c = 0; c < nc; c++) {
    const float* dr = dict + (size_t)cand[c] * DMODEL;
    double a = 0.0;
    #pragma unroll
    for (int i = 0; i < 16; i++) {
      int d = lane + i * 64;
      a += (double)xr[d] * (double)dr[d];
    }
    #pragma unroll
    for (int off = 32; off > 0; off >>= 1) a += __shfl_down(a, off, 64);
    if (lane == 0) csc[c] = a;
  }
  __syncthreads();
  if (lane == 0) {
    int best = 0;                          // all-masked -> np.argmax of equal values = 0
    if (nc > 0) {
      double bs = -1e300;
      best = NATOM;
      for (int c = 0; c < nc; c++)
        if (csc[c] > bs || (csc[c] == bs && cand[c] < best)) { bs = csc[c]; best = cand[c]; }
    }
    argout[t] = (float)best;               // harness reads d_out as float32
  }
}

// ---------------- kernel 3: recon partials = E @ dT^T over half the K range ----------------
// Split-K2: grid (4 n, 128 m, 2 k) = 1024 blocks -> 4 blocks/CU (LDS 40KB). bz=0 -> out,
// bz=1 -> P1 (dead ws region). No division here; combine kernel applies 1/lsum.
__launch_bounds__(256, 4)
__global__ void recon_kernel(const _Float16* __restrict__ E,
                             const _Float16* __restrict__ DT,
                             float* __restrict__ out,
                             float* __restrict__ P1) {
  __shared__ _Float16 lds[20480];          // 2 x (As 64x32 = 2048 + Bs 256x32 = 8192)
  const int tid  = threadIdx.x;
  const int lane = tid & 63;
  const int wave = tid >> 6;               // n-offset = wave*64
  const int m0 = blockIdx.y * 64;          // token tile
  const int n0 = blockIdx.x * 256;         // d_model tile
  const int kbase = blockIdx.z * (NATOM / 2);

  const int frow = lane & 15;
  const int fkc  = lane >> 4;

  f32x4 acc[4][4] = {};

  auto stage = [&](int k0, int b) {        // k0 absolute
    _Float16* As = lds + b * 10240;
    _Float16* Bs = As + 2048;
    {
      int L = tid;                         // 64 rows x 4 chunks
      int r = L >> 2, pc = L & 3;
      int c = pc ^ ((r >> 1) & 3);
      GLOAD_LDS16(E + (size_t)(m0 + r) * NATOM + k0 + c * 8, As + (size_t)L * 8);
    }
    #pragma unroll
    for (int i = 0; i < 4; i++) {
      int L = tid + i * 256;               // 256 rows x 4 chunks
      int r = L >> 2, pc = L & 3;
      int c = pc ^ ((r >> 1) & 3);
      GLOAD_LDS16(DT + (size_t)(n0 + r) * NATOM + k0 + c * 8, Bs + (size_t)L * 8);
    }
  };

  stage(kbase, 0);
  int cur = 0;
  const int NIT = (NATOM / 2) / 32;        // 256
  for (int it = 0; it < NIT; ++it) {
    __syncthreads();                       // buf[cur] ready (loads issued 1 compute-phase ago)
    if (it + 1 < NIT) stage(kbase + (it + 1) * 32, cur ^ 1);
    _Float16* As = lds + cur * 10240;
    _Float16* Bs = As + 2048;
    half8 af[4], bf[4];
    #pragma unroll
    for (int i = 0; i < 4; i++) {
      int ar = i * 16 + frow;
      int br = wave * 64 + i * 16 + frow;
      af[i] = *(const half8*)&As[ar * 32 + (fkc ^ ((ar >> 1) & 3)) * 8];
      bf[i] = *(const half8*)&Bs[br * 32 + (fkc ^ ((br >> 1) & 3)) * 8];
    }
    #pragma unroll
    for (int i = 0; i < 4; i++)
      #pragma unroll
      for (int j = 0; j < 4; j++)
        acc[i][j] = __builtin_amdgcn_mfma_f32_16x16x32_f16(af[i], bf[j], acc[i][j], 0, 0, 0);
    cur ^= 1;
  }

  float* P = blockIdx.z ? P1 : out;
  const int cr = (lane >> 4) * 4;
  const int cc = lane & 15;
  #pragma unroll
  for (int i = 0; i < 4; i++) {
    #pragma unroll
    for (int r = 0; r < 4; r++) {
      int lr = i * 16 + cr + r;
      #pragma unroll
      for (int j = 0; j < 4; j++) {
        int lc = wave * 64 + j * 16 + cc;
        P[(size_t)(m0 + lr) * DMODEL + (n0 + lc)] = acc[i][j][r];
      }
    }
  }
}

// ---------------- kernel 4: out = (out + P1) / lsum ----------------
__global__ void combine_kernel(float* __restrict__ out, const float* __restrict__ P1,
                               const float* __restrict__ lsum) {
  int t = blockIdx.x;
  int d = threadIdx.x;                     // 256 threads x float4 = 1024 dims
  float inv = 1.0f / lsum[t];
  float4* o = (float4*)(out + (size_t)t * DMODEL);
  const float4* p = (const float4*)(P1 + (size_t)t * DMODEL);
  float4 a = o[d], b = p[d];
  a.x = (a.x + b.x) * inv; a.y = (a.y + b.y) * inv;
  a.z = (a.z + b.z) * inv; a.w = (a.w + b.w) * inv;
  o[d] = a;
}

extern "C" void kernel_launch(void* const* d_in, const int* in_sizes, int n_in,
                              void* d_out, int out_size, void* d_ws, size_t ws_size,
                              hipStream_t stream) {
  const float* x    = (const float*)d_in[0];
  const float* dict = (const float*)d_in[1];
  const int*   mask = (const int*)d_in[2];
  float* recon  = (float*)d_out;
  float* argout = recon + (size_t)NTOK * DMODEL;

  // workspace layout (336 MB + 32 KB — proven size)
  char* w = (char*)d_ws;
  _Float16* Xh = (_Float16*)(w);                                 // 16 MB  [8192,1024]
  _Float16* Dh = (_Float16*)(w + (size_t)16  * 1024 * 1024);     // 32 MB  [16384,1024]
  _Float16* DT = (_Float16*)(w + (size_t)48  * 1024 * 1024);     // 32 MB  [1024,16384]
  _Float16* E  = (_Float16*)(w + (size_t)80  * 1024 * 1024);     // 256 MB [8192,16384]
  float*  lsum = (float*)  (w + (size_t)336 * 1024 * 1024);      // 32 KB
  float*  P1   = (float*)w;   // 32 MB split-K partial — reuses Xh+Dh[0:16MB], dead after score
  // Tmax (2 MB fp16) borrows the front of d_out; consumed by scan_lite before recon overwrites.
  _Float16* Tmax = (_Float16*)d_out;                             // [128][8192]

  cvt_f32_f16<<<dim3(NTOK * DMODEL / 4 / 256), 256, 0, stream>>>(x, Xh, NTOK * DMODEL / 4);
  transpose_dict<<<dim3(NATOM / 64, DMODEL / 64), 256, 0, stream>>>(dict, Dh, DT);
  zero_lsum<<<dim3(NTOK / 256), 256, 0, stream>>>(lsum);
  score_kernel<<<dim3(NATOM / 128, NTOK / 128), 256, 0, stream>>>(Xh, Dh, mask, E, lsum, Tmax);
  scan_lite<<<dim3(NTOK), 64, 0, stream>>>(E, Tmax, x, dict, argout);
  recon_kernel<<<dim3(DMODEL / 256, NTOK / 64, 2), 256, 0, stream>>>(E, DT, recon, P1);
  combine_kernel<<<dim3(NTOK), 256, 0, stream>>>(recon, P1, lsum);
}

// Round 5
// 1579.629 us; speedup vs baseline: 1.0868x; 1.0868x over previous
//
#include <hip/hip_runtime.h>

#define NTOK   8192
#define DMODEL 1024
#define NATOM  16384

typedef _Float16 half8  __attribute__((ext_vector_type(8)));
typedef _Float16 half4_t __attribute__((ext_vector_type(4)));
typedef float    f32x4  __attribute__((ext_vector_type(4)));

// async global->LDS, 16B per lane; LDS dest is wave-uniform base + lane*16
#define GLOAD_LDS16(gsrc, ldst) \
  __builtin_amdgcn_global_load_lds((const __attribute__((address_space(1))) unsigned int*)(gsrc), \
                                   (__attribute__((address_space(3))) unsigned int*)(ldst), 16, 0, 0)

// ---------------- prep: fp32 -> fp16 (x only) ----------------
__global__ void cvt_f32_f16(const float* __restrict__ in, _Float16* __restrict__ out, int n4) {
  int i = blockIdx.x * 256 + threadIdx.x;
  if (i >= n4) return;
  float4 v = ((const float4*)in)[i];
  half4_t h;
  h[0] = (_Float16)v.x; h[1] = (_Float16)v.y; h[2] = (_Float16)v.z; h[3] = (_Float16)v.w;
  ((half4_t*)out)[i] = h;
}

// ---------------- prep: dict f32 -> Dh [16384,1024] f16 AND dT [1024,16384] f16 ----------------
__global__ void transpose_dict(const float* __restrict__ dict,
                               _Float16* __restrict__ Dh, _Float16* __restrict__ dT) {
  __shared__ _Float16 tile[64][68];
  int a0 = blockIdx.x * 64;   // atom tile
  int d0 = blockIdx.y * 64;   // dim tile
  int tid = threadIdx.x;
  int c = tid & 63;
  int r0 = tid >> 6;
  #pragma unroll
  for (int i = 0; i < 16; i++) {
    int r = r0 + i * 4;
    _Float16 h = (_Float16)dict[(size_t)(a0 + r) * DMODEL + d0 + c];
    tile[r][c] = h;
    Dh[(size_t)(a0 + r) * DMODEL + d0 + c] = h;
  }
  __syncthreads();
  #pragma unroll
  for (int i = 0; i < 16; i++) {
    int rd = r0 + i * 4;
    dT[(size_t)(d0 + rd) * NATOM + a0 + c] = tile[c][rd];
  }
}

__global__ void zero_lsum(float* __restrict__ lsum) {
  lsum[blockIdx.x * 256 + threadIdx.x] = 0.0f;
}

// ---------------- prep: mask int32 [8192,16384] -> bitmask 16 MB ----------------
// Each thread packs 16 consecutive ints (4 x int4, coalesced) into one ushort (natural bit order).
__global__ void pack_mask(const int* __restrict__ mask, unsigned short* __restrict__ Mb) {
  size_t t = (size_t)blockIdx.x * 256 + threadIdx.x;
  const int4* p = (const int4*)(mask + t * 16);
  unsigned int m = 0;
  #pragma unroll
  for (int i = 0; i < 4; i++) {
    int4 v = p[i];
    m |= ((v.x != 0) ? 1u : 0u) << (i * 4 + 0);
    m |= ((v.y != 0) ? 1u : 0u) << (i * 4 + 1);
    m |= ((v.z != 0) ? 1u : 0u) << (i * 4 + 2);
    m |= ((v.w != 0) ? 1u : 0u) << (i * 4 + 3);
  }
  Mb[t] = (unsigned short)m;
}

// staging helper: 128 rows x 32 k, XOR k-chunk swizzle on the global source side
__device__ __forceinline__ void stage_ab(const _Float16* __restrict__ A,
                                         const _Float16* __restrict__ B,
                                         _Float16* As, _Float16* Bs,
                                         size_t arow0, size_t brow0, size_t ldk,
                                         int k0, int tid) {
  #pragma unroll
  for (int i = 0; i < 2; i++) {
    int L = tid + i * 256;               // 0..511 = 128 rows x 4 chunks
    int r = L >> 2, pc = L & 3;
    int c = pc ^ ((r >> 1) & 3);
    GLOAD_LDS16(A + (arow0 + r) * ldk + k0 + c * 8, As + (size_t)L * 8);
    GLOAD_LDS16(B + (brow0 + r) * ldk + k0 + c * 8, Bs + (size_t)L * 8);
  }
}

// ---------------- kernel 1: E = mask ? exp(x @ dict^T) : 0, + row-tile sum/max ----------------
// 128x128 tile, BK=32, double-buffered staging, 4 waves (2x2), mfma_f32_16x16x32_f16.
// Mask comes pre-packed as bits (8B per 4 rows in the epilogue, L3-resident) — the 512 MB
// int32 stream never touches this kernel. NOTE: no tight launch_bounds — acc uses 64 AGPRs;
// capping unified regs at 128 caused scratch spills (round-4 regression, +1 GB HBM).
__launch_bounds__(256, 2)
__global__ void score_kernel(const _Float16* __restrict__ Xh,
                             const _Float16* __restrict__ Dh,
                             const unsigned long long* __restrict__ Mb,  // [8192][256] bit rows
                             _Float16* __restrict__ E,
                             float* __restrict__ lsum,
                             _Float16* __restrict__ Tmax) {   // [8192 tokens][128 tiles]
  __shared__ _Float16 lds[17408];          // dbuf staging 2x8192; epilogue overlays 128x136
  const int tid  = threadIdx.x;
  const int lane = tid & 63;
  const int wave = tid >> 6;
  const int wm = wave >> 1, wn = wave & 1;
  const int m0 = blockIdx.y * 128;         // token tile
  const int n0 = blockIdx.x * 128;         // atom tile

  const int frow = lane & 15;
  const int fkc  = lane >> 4;

  f32x4 acc[4][4] = {};

  stage_ab(Xh, Dh, lds, lds + 4096, m0, n0, DMODEL, 0, tid);
  int cur = 0;
  for (int it = 0; it < DMODEL / 32; ++it) {
    __syncthreads();                       // drains vmcnt: buf[cur] ready (issued 1 compute ago)
    if (it + 1 < DMODEL / 32)
      stage_ab(Xh, Dh, lds + (cur ^ 1) * 8192, lds + (cur ^ 1) * 8192 + 4096,
               m0, n0, DMODEL, (it + 1) * 32, tid);
    _Float16* As = lds + cur * 8192;
    _Float16* Bs = As + 4096;
    half8 af[4], bf[4];
    #pragma unroll
    for (int i = 0; i < 4; i++) {
      int ar = wm * 64 + i * 16 + frow;
      int br = wn * 64 + i * 16 + frow;
      af[i] = *(const half8*)&As[ar * 32 + (fkc ^ ((ar >> 1) & 3)) * 8];
      bf[i] = *(const half8*)&Bs[br * 32 + (fkc ^ ((br >> 1) & 3)) * 8];
    }
    #pragma unroll
    for (int i = 0; i < 4; i++)
      #pragma unroll
      for (int j = 0; j < 4; j++)
        acc[i][j] = __builtin_amdgcn_mfma_f32_16x16x32_f16(af[i], bf[j], acc[i][j], 0, 0, 0);
    cur ^= 1;
  }

  __syncthreads();
  // epilogue: C/D layout col=lane&15, row=(lane>>4)*4+reg. packed-mask bit + exp -> LDS -> store.
  const int cr = (lane >> 4) * 4;
  const int cc = lane & 15;
  #pragma unroll
  for (int i = 0; i < 4; i++) {
    unsigned long long rb[4];
    #pragma unroll
    for (int r = 0; r < 4; r++)
      rb[r] = Mb[(size_t)(m0 + wm * 64 + i * 16 + cr + r) * 256 + (n0 >> 6) + wn];
    #pragma unroll
    for (int j = 0; j < 4; j++) {
      #pragma unroll
      for (int r = 0; r < 4; r++) {
        int lr = wm * 64 + i * 16 + cr + r;
        int lc = wn * 64 + j * 16 + cc;
        unsigned int mk = (unsigned int)(rb[r] >> (j * 16 + cc)) & 1u;
        float e = mk ? __expf(acc[i][j][r]) : 0.0f;   // scores bounded |s|<=11: no max-subtract
        lds[lr * 136 + lc] = (_Float16)e;
      }
    }
  }
  __syncthreads();
  // coalesced E store
  #pragma unroll
  for (int i = 0; i < 8; i++) {
    int chunk = i * 256 + tid;
    int r  = chunk >> 4;
    int c8 = (chunk & 15) * 8;
    *(half8*)&E[(size_t)(m0 + r) * NATOM + n0 + c8] = *(const half8*)&lds[r * 136 + c8];
  }
  // per-row partial sum (-> atomic lsum) and tile max (-> Tmax, token-major for coalesced scan)
  {
    int r = tid >> 1, h = tid & 1;
    const _Float16* rowp = &lds[r * 136 + h * 64];
    float s = 0.0f, m = 0.0f;
    #pragma unroll
    for (int i = 0; i < 8; i++) {
      half8 v = *(const half8*)&rowp[i * 8];
      #pragma unroll
      for (int j = 0; j < 8; j++) { float f = (float)v[j]; s += f; m = fmaxf(m, f); }
    }
    s += __shfl_xor(s, 1, 64);
    m = fmaxf(m, __shfl_xor(m, 1, 64));
    if (h == 0) {
      atomicAdd(&lsum[m0 + r], s);
      Tmax[(size_t)(m0 + r) * 128 + blockIdx.x] = (_Float16)m;
    }
  }
}

// ---------------- kernel 2: sparse argmax scan (1 wave/token, 4 tokens/block) ----------------
// Tile maxes are token-major -> coalesced. Only tiles with max >= 0.98*gmax get their 128 E
// values re-read (margin = 84 sigma of fp16-GEMM score error), then exact fp64 re-eval,
// ties -> lowest index (np.argmax semantics). Per-wave LDS state, no barriers needed.
__global__ void scan_lite(const _Float16* __restrict__ E,
                          const _Float16* __restrict__ Tmax,
                          const float* __restrict__ x,
                          const float* __restrict__ dict,
                          float* __restrict__ argout) {
  const int w = threadIdx.x >> 6;
  const int lane = threadIdx.x & 63;
  const int t = blockIdx.x * 4 + w;
  const _Float16* tm = Tmax + (size_t)t * 128;
  float m0 = (float)tm[lane];
  float m1 = (float)tm[64 + lane];
  float mx = fmaxf(m0, m1);
  #pragma unroll
  for (int off = 32; off > 0; off >>= 1) mx = fmaxf(mx, __shfl_xor(mx, off, 64));

  __shared__ int cnt[4];
  __shared__ int cand[4][32];
  __shared__ double csc[4][32];
  if (lane == 0) cnt[w] = 0;

  if (mx > 0.0f) {
    float thr = 0.98f * mx;
    unsigned long long q0 = __ballot(m0 >= thr);
    unsigned long long q1 = __ballot(m1 >= thr);
    while (q0 | q1) {
      int tile;
      if (q0) { tile = __ffsll(q0) - 1; q0 &= q0 - 1; }
      else    { tile = 64 + __ffsll(q1) - 1; q1 &= q1 - 1; }
      const _Float16* ep = E + (size_t)t * NATOM + tile * 128;
      float e0 = (float)ep[lane], e1 = (float)ep[64 + lane];
      if (e0 >= thr) { int p = atomicAdd(&cnt[w], 1); if (p < 32) cand[w][p] = tile * 128 + lane; }
      if (e1 >= thr) { int p = atomicAdd(&cnt[w], 1); if (p < 32) cand[w][p] = tile * 128 + 64 + lane; }
    }
  }
  int nc = min(cnt[w], 32);
  const float* xr = x + (size_t)t * DMODEL;
  for (int c = 0; c < nc; c++) {
    const float* dr = dict + (size_t)cand[w][c] * DMODEL;
    double a = 0.0;
    #pragma unroll
    for (int i = 0; i < 16; i++) {
      int d = lane + i * 64;
      a += (double)xr[d] * (double)dr[d];
    }
    #pragma unroll
    for (int off = 32; off > 0; off >>= 1) a += __shfl_down(a, off, 64);
    if (lane == 0) csc[w][c] = a;
  }
  if (lane == 0) {
    int best = 0;                          // all-masked -> np.argmax of equal values = 0
    if (nc > 0) {
      double bs = -1e300;
      best = NATOM;
      for (int c = 0; c < nc; c++)
        if (csc[w][c] > bs || (csc[w][c] == bs && cand[w][c] < best)) { bs = csc[w][c]; best = cand[w][c]; }
    }
    argout[t] = (float)best;               // harness reads d_out as float32
  }
}

// ---------------- kernel 3: recon partials = E @ dT^T over half the K range ----------------
// Split-K2: grid (4 n, 128 m, 2 k) = 1024 blocks -> 4 blocks/CU (LDS 40KB). bz=0 -> out,
// bz=1 -> P1 (dead ws region). No division here; combine kernel applies 1/lsum.
// VGPR check: acc 64 AGPR + ~56 VGPR = 120 <= 128 cap at 4 waves/EU — no spill (r4 verified).
__launch_bounds__(256, 4)
__global__ void recon_kernel(const _Float16* __restrict__ E,
                             const _Float16* __restrict__ DT,
                             float* __restrict__ out,
                             float* __restrict__ P1) {
  __shared__ _Float16 lds[20480];          // 2 x (As 64x32 = 2048 + Bs 256x32 = 8192)
  const int tid  = threadIdx.x;
  const int lane = tid & 63;
  const int wave = tid >> 6;               // n-offset = wave*64
  const int m0 = blockIdx.y * 64;          // token tile
  const int n0 = blockIdx.x * 256;         // d_model tile
  const int kbase = blockIdx.z * (NATOM / 2);

  const int frow = lane & 15;
  const int fkc  = lane >> 4;

  f32x4 acc[4][4] = {};

  auto stage = [&](int k0, int b) {        // k0 absolute
    _Float16* As = lds + b * 10240;
    _Float16* Bs = As + 2048;
    {
      int L = tid;                         // 64 rows x 4 chunks
      int r = L >> 2, pc = L & 3;
      int c = pc ^ ((r >> 1) & 3);
      GLOAD_LDS16(E + (size_t)(m0 + r) * NATOM + k0 + c * 8, As + (size_t)L * 8);
    }
    #pragma unroll
    for (int i = 0; i < 4; i++) {
      int L = tid + i * 256;               // 256 rows x 4 chunks
      int r = L >> 2, pc = L & 3;
      int c = pc ^ ((r >> 1) & 3);
      GLOAD_LDS16(DT + (size_t)(n0 + r) * NATOM + k0 + c * 8, Bs + (size_t)L * 8);
    }
  };

  stage(kbase, 0);
  int cur = 0;
  const int NIT = (NATOM / 2) / 32;        // 256
  for (int it = 0; it < NIT; ++it) {
    __syncthreads();                       // buf[cur] ready (loads issued 1 compute-phase ago)
    if (it + 1 < NIT) stage(kbase + (it + 1) * 32, cur ^ 1);
    _Float16* As = lds + cur * 10240;
    _Float16* Bs = As + 2048;
    half8 af[4], bf[4];
    #pragma unroll
    for (int i = 0; i < 4; i++) {
      int ar = i * 16 + frow;
      int br = wave * 64 + i * 16 + frow;
      af[i] = *(const half8*)&As[ar * 32 + (fkc ^ ((ar >> 1) & 3)) * 8];
      bf[i] = *(const half8*)&Bs[br * 32 + (fkc ^ ((br >> 1) & 3)) * 8];
    }
    #pragma unroll
    for (int i = 0; i < 4; i++)
      #pragma unroll
      for (int j = 0; j < 4; j++)
        acc[i][j] = __builtin_amdgcn_mfma_f32_16x16x32_f16(af[i], bf[j], acc[i][j], 0, 0, 0);
    cur ^= 1;
  }

  float* P = blockIdx.z ? P1 : out;
  const int cr = (lane >> 4) * 4;
  const int cc = lane & 15;
  #pragma unroll
  for (int i = 0; i < 4; i++) {
    #pragma unroll
    for (int r = 0; r < 4; r++) {
      int lr = i * 16 + cr + r;
      #pragma unroll
      for (int j = 0; j < 4; j++) {
        int lc = wave * 64 + j * 16 + cc;
        P[(size_t)(m0 + lr) * DMODEL + (n0 + lc)] = acc[i][j][r];
      }
    }
  }
}

// ---------------- kernel 4: out = (out + P1) / lsum ----------------
__global__ void combine_kernel(float* __restrict__ out, const float* __restrict__ P1,
                               const float* __restrict__ lsum) {
  int t = blockIdx.x;
  int d = threadIdx.x;                     // 256 threads x float4 = 1024 dims
  float inv = 1.0f / lsum[t];
  float4* o = (float4*)(out + (size_t)t * DMODEL);
  const float4* p = (const float4*)(P1 + (size_t)t * DMODEL);
  float4 a = o[d], b = p[d];
  a.x = (a.x + b.x) * inv; a.y = (a.y + b.y) * inv;
  a.z = (a.z + b.z) * inv; a.w = (a.w + b.w) * inv;
  o[d] = a;
}

extern "C" void kernel_launch(void* const* d_in, const int* in_sizes, int n_in,
                              void* d_out, int out_size, void* d_ws, size_t ws_size,
                              hipStream_t stream) {
  const float* x    = (const float*)d_in[0];
  const float* dict = (const float*)d_in[1];
  const int*   mask = (const int*)d_in[2];
  float* recon  = (float*)d_out;
  float* argout = recon + (size_t)NTOK * DMODEL;

  // workspace layout (336 MB + 32 KB — proven size)
  char* w = (char*)d_ws;
  _Float16* Xh = (_Float16*)(w);                                 // 16 MB  [8192,1024]
  _Float16* Dh = (_Float16*)(w + (size_t)16  * 1024 * 1024);     // 32 MB  [16384,1024]
  _Float16* DT = (_Float16*)(w + (size_t)48  * 1024 * 1024);     // 32 MB  [1024,16384]
  _Float16* E  = (_Float16*)(w + (size_t)80  * 1024 * 1024);     // 256 MB [8192,16384]
  float*  lsum = (float*)  (w + (size_t)336 * 1024 * 1024);      // 32 KB
  float*  P1   = (float*)w;   // 32 MB split-K partial — reuses Xh+Dh[0:16MB], dead after score
  // d_out region borrows (all consumed before recon_kernel/combine overwrite, stream-ordered):
  _Float16* Tmax = (_Float16*)d_out;                             // 2 MB  [8192][128]
  unsigned short* Mb = (unsigned short*)((char*)d_out + 2 * 1024 * 1024);  // 16 MB bitmask

  cvt_f32_f16<<<dim3(NTOK * DMODEL / 4 / 256), 256, 0, stream>>>(x, Xh, NTOK * DMODEL / 4);
  transpose_dict<<<dim3(NATOM / 64, DMODEL / 64), 256, 0, stream>>>(dict, Dh, DT);
  pack_mask<<<dim3((size_t)NTOK * NATOM / 16 / 256), 256, 0, stream>>>(mask, Mb);
  zero_lsum<<<dim3(NTOK / 256), 256, 0, stream>>>(lsum);
  score_kernel<<<dim3(NATOM / 128, NTOK / 128), 256, 0, stream>>>(
      Xh, Dh, (const unsigned long long*)Mb, E, lsum, Tmax);
  scan_lite<<<dim3(NTOK / 4), 256, 0, stream>>>(E, Tmax, x, dict, argout);
  recon_kernel<<<dim3(DMODEL / 256, NTOK / 64, 2), 256, 0, stream>>>(E, DT, recon, P1);
  combine_kernel<<<dim3(NTOK), 256, 0, stream>>>(recon, P1, lsum);
}